// Round 1
// baseline (10437.998 us; speedup 1.0000x reference)
//
#include <hip/hip_runtime.h>
#include <hip/hip_bf16.h>

#define NN 100000

static inline size_t align_up(size_t x, size_t a) { return (x + a - 1) & ~(a - 1); }

__global__ __launch_bounds__(256) void deg_count_kernel(const int* __restrict__ dst,
                                                        float* __restrict__ deg, int E) {
    int t = blockIdx.x * 256 + threadIdx.x;
    if (t < E) atomicAdd(&deg[dst[t]], 1.0f);
}

__global__ __launch_bounds__(256) void dinv_kernel(float* __restrict__ deg, int n) {
    int t = blockIdx.x * 256 + threadIdx.x;
    if (t < n) deg[t] = rsqrtf(deg[t] + 1.0f);
}

__global__ __launch_bounds__(256) void norm_kernel(const int* __restrict__ src,
                                                   const int* __restrict__ dst,
                                                   const float* __restrict__ dinv,
                                                   float* __restrict__ norm, int E) {
    int t = blockIdx.x * 256 + threadIdx.x;
    if (t < E) norm[t] = dinv[src[t]] * dinv[dst[t]];
}

// C[M,N] = A[M,K] @ B[K,N], fp32, 64x64 tile, 256 threads, 4x4 per thread.
__global__ __launch_bounds__(256) void gemm64_kernel(const float* __restrict__ A,
                                                     const float* __restrict__ B,
                                                     float* __restrict__ C,
                                                     int M, int K, int N) {
    __shared__ float As[16][65];   // [k][m], pad to break bank conflicts
    __shared__ float Bs[16][68];   // [k][n], 68*4=272 bytes row stride (16B aligned)
    const int bm = blockIdx.x * 64;
    const int bn = blockIdx.y * 64;
    const int tid = threadIdx.x;
    const int tx = tid & 15;       // output col group
    const int ty = tid >> 4;       // output row group
    const int arow = tid >> 2;     // 0..63
    const int akq  = (tid & 3) << 2;  // 0,4,8,12
    const int brow = tid >> 4;     // 0..15
    const int bcol = (tid & 15) << 2; // 0..60
    const bool avalid = (bm + arow) < M;
    const float* aptr = A + (size_t)(bm + arow) * K + akq;
    const float* bptr = B + (size_t)brow * N + bn + bcol;
    float acc[4][4] = {};
    for (int k0 = 0; k0 < K; k0 += 16) {
        float4 av = make_float4(0.f, 0.f, 0.f, 0.f);
        if (avalid) av = *(const float4*)(aptr + k0);
        float4 bv = *(const float4*)(bptr + (size_t)k0 * N);
        __syncthreads();
        As[akq + 0][arow] = av.x;
        As[akq + 1][arow] = av.y;
        As[akq + 2][arow] = av.z;
        As[akq + 3][arow] = av.w;
        *(float4*)&Bs[brow][bcol] = bv;
        __syncthreads();
        #pragma unroll
        for (int k = 0; k < 16; ++k) {
            float a0 = As[k][ty * 4 + 0];
            float a1 = As[k][ty * 4 + 1];
            float a2 = As[k][ty * 4 + 2];
            float a3 = As[k][ty * 4 + 3];
            float4 b = *(float4*)&Bs[k][tx * 4];
            acc[0][0] += a0 * b.x; acc[0][1] += a0 * b.y; acc[0][2] += a0 * b.z; acc[0][3] += a0 * b.w;
            acc[1][0] += a1 * b.x; acc[1][1] += a1 * b.y; acc[1][2] += a1 * b.z; acc[1][3] += a1 * b.w;
            acc[2][0] += a2 * b.x; acc[2][1] += a2 * b.y; acc[2][2] += a2 * b.z; acc[2][3] += a2 * b.w;
            acc[3][0] += a3 * b.x; acc[3][1] += a3 * b.y; acc[3][2] += a3 * b.z; acc[3][3] += a3 * b.w;
        }
    }
    #pragma unroll
    for (int i = 0; i < 4; ++i) {
        int row = bm + ty * 4 + i;
        if (row < M) {
            *(float4*)&C[(size_t)row * N + bn + tx * 4] =
                make_float4(acc[i][0], acc[i][1], acc[i][2], acc[i][3]);
        }
    }
}

// agg[dst] += h[src] * norm, one float4 per thread. F = 4<<LOGFQ features.
template<int LOGFQ>
__global__ __launch_bounds__(256) void scatter_kernel(const float* __restrict__ h,
        const int* __restrict__ src, const int* __restrict__ dst,
        const float* __restrict__ norm, float* __restrict__ agg, int E) {
    const int FQ = 1 << LOGFQ;
    int t = blockIdx.x * 256 + threadIdx.x;
    int total = E << LOGFQ;
    if (t >= total) return;
    int e = t >> LOGFQ;
    int c = (t & (FQ - 1)) << 2;
    int s = src[e], d = dst[e];
    float nrm = norm[e];
    const float4 v = *(const float4*)&h[((size_t)s << (LOGFQ + 2)) + c];
    float* ap = &agg[((size_t)d << (LOGFQ + 2)) + c];
    atomicAdd(ap + 0, v.x * nrm);
    atomicAdd(ap + 1, v.y * nrm);
    atomicAdd(ap + 2, v.z * nrm);
    atomicAdd(ap + 3, v.w * nrm);
}

// agg = (relu?)(agg + h*dinv^2 + bias), in place. n = N * (F/4) float4s.
template<int LOGFQ, bool RELU>
__global__ __launch_bounds__(256) void finish_kernel(float* __restrict__ agg,
        const float* __restrict__ h, const float* __restrict__ dinv,
        const float* __restrict__ bias, int n) {
    int t = blockIdx.x * 256 + threadIdx.x;
    if (t >= n) return;
    int row = t >> LOGFQ;
    int c = (t & ((1 << LOGFQ) - 1)) << 2;
    float di = dinv[row];
    float d2 = di * di;
    float4 a = *(float4*)&agg[(size_t)t << 2];
    const float4 hv = *(const float4*)&h[(size_t)t << 2];
    const float4 b = *(const float4*)&bias[c];
    float4 r;
    r.x = a.x + hv.x * d2 + b.x;
    r.y = a.y + hv.y * d2 + b.y;
    r.z = a.z + hv.z * d2 + b.z;
    r.w = a.w + hv.w * d2 + b.w;
    if (RELU) {
        r.x = fmaxf(r.x, 0.f); r.y = fmaxf(r.y, 0.f);
        r.z = fmaxf(r.z, 0.f); r.w = fmaxf(r.w, 0.f);
    }
    *(float4*)&agg[(size_t)t << 2] = r;
}

// out[row] = log_softmax(agg + h*dinv^2 + bias), 64 features == 64 lanes.
__global__ __launch_bounds__(256) void logsoftmax_kernel(const float* __restrict__ agg,
        const float* __restrict__ h, const float* __restrict__ dinv,
        const float* __restrict__ bias, float* __restrict__ out, int N) {
    int lane = threadIdx.x & 63;
    int row = blockIdx.x * 4 + (threadIdx.x >> 6);
    if (row >= N) return;
    float di = dinv[row];
    size_t idx = (size_t)row * 64 + lane;
    float v = agg[idx] + h[idx] * di * di + bias[lane];
    float m = v;
    #pragma unroll
    for (int o = 32; o; o >>= 1) m = fmaxf(m, __shfl_xor(m, o, 64));
    float e = __expf(v - m);
    float s = e;
    #pragma unroll
    for (int o = 32; o; o >>= 1) s += __shfl_xor(s, o, 64);
    out[idx] = v - m - __logf(s);
}

extern "C" void kernel_launch(void* const* d_in, const int* in_sizes, int n_in,
                              void* d_out, int out_size, void* d_ws, size_t ws_size,
                              hipStream_t stream) {
    const float* x  = (const float*)d_in[0];
    const int*   ei = (const int*)d_in[1];
    const float* W1 = (const float*)d_in[2];
    const float* b1 = (const float*)d_in[3];
    const float* W2 = (const float*)d_in[4];
    const float* b2 = (const float*)d_in[5];
    const float* W3 = (const float*)d_in[6];
    const float* b3 = (const float*)d_in[7];
    const int E = in_sizes[1] / 2;
    const int* src = ei;
    const int* dst = ei + E;
    const int N = NN;

    // workspace layout
    char* ws = (char*)d_ws;
    float* dinv = (float*)ws;                 ws += align_up((size_t)N * 4, 256);
    float* norm = (float*)ws;                 ws += align_up((size_t)E * 4, 256);
    float* bufA = (float*)ws;                 ws += (size_t)N * 256 * 4;  // h1, then h2
    float* bufB = (float*)ws;                 ws += (size_t)N * 256 * 4;  // agg1/act1; later h3+agg3
    float* bufC = (float*)ws;                 ws += (size_t)N * 128 * 4;  // agg2/act2
    float* h3   = bufB;                       // reuse after gemm2 consumed bufB
    float* agg3 = bufB + (size_t)N * 64;
    float* out  = (float*)d_out;

    // zero what atomics accumulate into
    hipMemsetAsync(dinv, 0, (size_t)N * 4, stream);
    hipMemsetAsync(bufB, 0, (size_t)N * 256 * 4, stream);
    hipMemsetAsync(bufC, 0, (size_t)N * 128 * 4, stream);

    // degree -> dinv -> per-edge norm (shared by all 3 layers)
    deg_count_kernel<<<(E + 255) / 256, 256, 0, stream>>>(dst, dinv, E);
    dinv_kernel<<<(N + 255) / 256, 256, 0, stream>>>(dinv, N);
    norm_kernel<<<(E + 255) / 256, 256, 0, stream>>>(src, dst, dinv, norm, E);

    const int MB = (N + 63) / 64;  // 1563

    // ---- layer 1: 512 -> 256 ----
    gemm64_kernel<<<dim3(MB, 4), 256, 0, stream>>>(x, W1, bufA, N, 512, 256);
    scatter_kernel<6><<<((E << 6) + 255) / 256, 256, 0, stream>>>(bufA, src, dst, norm, bufB, E);
    finish_kernel<6, true><<<(N * 64 + 255) / 256, 256, 0, stream>>>(bufB, bufA, dinv, b1, N * 64);

    // ---- layer 2: 256 -> 128 ----
    gemm64_kernel<<<dim3(MB, 2), 256, 0, stream>>>(bufB, W2, bufA, N, 256, 128);
    scatter_kernel<5><<<((E << 5) + 255) / 256, 256, 0, stream>>>(bufA, src, dst, norm, bufC, E);
    finish_kernel<5, true><<<(N * 32 + 255) / 256, 256, 0, stream>>>(bufC, bufA, dinv, b2, N * 32);

    // ---- layer 3: 128 -> 64 ----
    gemm64_kernel<<<dim3(MB, 1), 256, 0, stream>>>(bufC, W3, h3, N, 128, 64);
    hipMemsetAsync(agg3, 0, (size_t)N * 64 * 4, stream);
    scatter_kernel<4><<<((E << 4) + 255) / 256, 256, 0, stream>>>(h3, src, dst, norm, agg3, E);
    logsoftmax_kernel<<<(N + 3) / 4, 256, 0, stream>>>(agg3, h3, dinv, b3, out, N);
}

// Round 3
// 1689.643 us; speedup vs baseline: 6.1776x; 6.1776x over previous
//
#include <hip/hip_runtime.h>
#include <hip/hip_bf16.h>

#define NN 100000

static inline size_t align_up(size_t x, size_t a) { return (x + a - 1) & ~(a - 1); }

// ---------------- preprocessing: CSR build (per call, graph-capture safe) ----------------

__global__ __launch_bounds__(256) void deg_count_kernel(const int* __restrict__ dst,
                                                        int* __restrict__ deg, int E) {
    int t = blockIdx.x * 256 + threadIdx.x;
    if (t < E) atomicAdd(&deg[dst[t]], 1);
}

__global__ __launch_bounds__(256) void dinv_kernel(const int* __restrict__ deg,
                                                   float* __restrict__ dinv, int n) {
    int t = blockIdx.x * 256 + threadIdx.x;
    if (t < n) dinv[t] = rsqrtf((float)deg[t] + 1.0f);
}

// single-workgroup exclusive scan: deg[0..n) -> rowptr[0..n]
__global__ __launch_bounds__(1024) void scan_kernel(const int* __restrict__ deg,
                                                    int* __restrict__ rowptr, int n) {
    __shared__ int sums[1024];
    const int t = threadIdx.x;
    const int C = (n + 1023) >> 10;
    const int lo = t * C;
    const int hi = min(lo + C, n);
    int s = 0;
    for (int i = lo; i < hi; ++i) s += deg[i];
    sums[t] = s;
    __syncthreads();
    // Hillis-Steele inclusive scan over 1024 partials
    for (int d = 1; d < 1024; d <<= 1) {
        int v = (t >= d) ? sums[t - d] : 0;
        __syncthreads();
        sums[t] += v;
        __syncthreads();
    }
    int off = sums[t] - s;  // exclusive prefix for this chunk
    for (int i = lo; i < hi; ++i) { rowptr[i] = off; off += deg[i]; }
    if (hi == n) rowptr[n] = off;  // benign multi-writer (same value)
}

// scatter edges into dst-sorted order; fold norm computation in
__global__ __launch_bounds__(256) void reorder_kernel(const int* __restrict__ src,
        const int* __restrict__ dst, const int* __restrict__ rowptr,
        int* __restrict__ cursor, const float* __restrict__ dinv,
        int* __restrict__ esrc, float* __restrict__ enorm, int E) {
    int e = blockIdx.x * 256 + threadIdx.x;
    if (e >= E) return;
    int s = src[e], d = dst[e];
    int pos = rowptr[d] + atomicAdd(&cursor[d], 1);
    esrc[pos] = s;
    enorm[pos] = dinv[s] * dinv[d];
}

// ---------------- GEMM: C[M,N] = A[M,K] @ B[K,N], fp32, 64x64 tile ----------------

__global__ __launch_bounds__(256) void gemm64_kernel(const float* __restrict__ A,
                                                     const float* __restrict__ B,
                                                     float* __restrict__ C,
                                                     int M, int K, int N) {
    __shared__ float As[16][65];
    __shared__ float Bs[16][68];
    const int bm = blockIdx.x * 64;
    const int bn = blockIdx.y * 64;
    const int tid = threadIdx.x;
    const int tx = tid & 15;
    const int ty = tid >> 4;
    const int arow = tid >> 2;
    const int akq  = (tid & 3) << 2;
    const int brow = tid >> 4;
    const int bcol = (tid & 15) << 2;
    const bool avalid = (bm + arow) < M;
    const float* aptr = A + (size_t)(bm + arow) * K + akq;
    const float* bptr = B + (size_t)brow * N + bn + bcol;
    float acc[4][4] = {};
    for (int k0 = 0; k0 < K; k0 += 16) {
        float4 av = make_float4(0.f, 0.f, 0.f, 0.f);
        if (avalid) av = *(const float4*)(aptr + k0);
        float4 bv = *(const float4*)(bptr + (size_t)k0 * N);
        __syncthreads();
        As[akq + 0][arow] = av.x;
        As[akq + 1][arow] = av.y;
        As[akq + 2][arow] = av.z;
        As[akq + 3][arow] = av.w;
        *(float4*)&Bs[brow][bcol] = bv;
        __syncthreads();
        #pragma unroll
        for (int k = 0; k < 16; ++k) {
            float a0 = As[k][ty * 4 + 0];
            float a1 = As[k][ty * 4 + 1];
            float a2 = As[k][ty * 4 + 2];
            float a3 = As[k][ty * 4 + 3];
            float4 b = *(float4*)&Bs[k][tx * 4];
            acc[0][0] += a0 * b.x; acc[0][1] += a0 * b.y; acc[0][2] += a0 * b.z; acc[0][3] += a0 * b.w;
            acc[1][0] += a1 * b.x; acc[1][1] += a1 * b.y; acc[1][2] += a1 * b.z; acc[1][3] += a1 * b.w;
            acc[2][0] += a2 * b.x; acc[2][1] += a2 * b.y; acc[2][2] += a2 * b.z; acc[2][3] += a2 * b.w;
            acc[3][0] += a3 * b.x; acc[3][1] += a3 * b.y; acc[3][2] += a3 * b.z; acc[3][3] += a3 * b.w;
        }
    }
    #pragma unroll
    for (int i = 0; i < 4; ++i) {
        int row = bm + ty * 4 + i;
        if (row < M) {
            *(float4*)&C[(size_t)row * N + bn + tx * 4] =
                make_float4(acc[i][0], acc[i][1], acc[i][2], acc[i][3]);
        }
    }
}

// ---------------- aggregation: gather over CSR, one wave per node ----------------
// out[n] = relu( sum_{e in row n} h[esrc[e]]*enorm[e] + h[n]*dinv[n]^2 + bias )
// F = 64*VEC features; lane l owns features [l*VEC, l*VEC+VEC)

template<int VEC, bool RELU>
__global__ __launch_bounds__(256) void agg_kernel(const float* __restrict__ h,
        const int* __restrict__ rowptr, const int* __restrict__ esrc,
        const float* __restrict__ enorm, const float* __restrict__ dinv,
        const float* __restrict__ bias, float* __restrict__ out, int N) {
    const int node = blockIdx.x * 4 + (threadIdx.x >> 6);
    if (node >= N) return;
    const int lane = threadIdx.x & 63;
    const int F = 64 * VEC;
    const float di = dinv[node];
    const float d2 = di * di;
    float acc[VEC];
    {
        const float* hp = h + (size_t)node * F + lane * VEC;
        const float* bp = bias + lane * VEC;
        if constexpr (VEC == 4) {
            float4 v = *(const float4*)hp; float4 b = *(const float4*)bp;
            acc[0] = v.x * d2 + b.x; acc[1] = v.y * d2 + b.y;
            acc[2] = v.z * d2 + b.z; acc[3] = v.w * d2 + b.w;
        } else if constexpr (VEC == 2) {
            float2 v = *(const float2*)hp; float2 b = *(const float2*)bp;
            acc[0] = v.x * d2 + b.x; acc[1] = v.y * d2 + b.y;
        } else {
            acc[0] = hp[0] * d2 + bp[0];
        }
    }
    const int e0 = rowptr[node], e1 = rowptr[node + 1];
    for (int e = e0; e < e1; ++e) {
        const int s = esrc[e];
        const float w = enorm[e];
        const float* sp = h + (size_t)s * F + lane * VEC;
        if constexpr (VEC == 4) {
            float4 v = *(const float4*)sp;
            acc[0] += v.x * w; acc[1] += v.y * w; acc[2] += v.z * w; acc[3] += v.w * w;
        } else if constexpr (VEC == 2) {
            float2 v = *(const float2*)sp;
            acc[0] += v.x * w; acc[1] += v.y * w;
        } else {
            acc[0] += sp[0] * w;
        }
    }
    float* op = out + (size_t)node * F + lane * VEC;
    if constexpr (VEC == 4) {
        float4 r;
        r.x = RELU ? fmaxf(acc[0], 0.f) : acc[0];
        r.y = RELU ? fmaxf(acc[1], 0.f) : acc[1];
        r.z = RELU ? fmaxf(acc[2], 0.f) : acc[2];
        r.w = RELU ? fmaxf(acc[3], 0.f) : acc[3];
        *(float4*)op = r;
    } else if constexpr (VEC == 2) {
        float2 r;
        r.x = RELU ? fmaxf(acc[0], 0.f) : acc[0];
        r.y = RELU ? fmaxf(acc[1], 0.f) : acc[1];
        *(float2*)op = r;
    } else {
        op[0] = RELU ? fmaxf(acc[0], 0.f) : acc[0];
    }
}

// final layer: aggregation + log_softmax fused, F=64, lane==feature
__global__ __launch_bounds__(256) void agg_lsm_kernel(const float* __restrict__ h,
        const int* __restrict__ rowptr, const int* __restrict__ esrc,
        const float* __restrict__ enorm, const float* __restrict__ dinv,
        const float* __restrict__ bias, float* __restrict__ out, int N) {
    const int node = blockIdx.x * 4 + (threadIdx.x >> 6);
    if (node >= N) return;
    const int lane = threadIdx.x & 63;
    const float di = dinv[node];
    float acc = h[(size_t)node * 64 + lane] * di * di + bias[lane];
    const int e0 = rowptr[node], e1 = rowptr[node + 1];
    for (int e = e0; e < e1; ++e) {
        acc += h[(size_t)esrc[e] * 64 + lane] * enorm[e];
    }
    float m = acc;
    #pragma unroll
    for (int o = 32; o; o >>= 1) m = fmaxf(m, __shfl_xor(m, o, 64));
    float ex = __expf(acc - m);
    float s = ex;
    #pragma unroll
    for (int o = 32; o; o >>= 1) s += __shfl_xor(s, o, 64);
    out[(size_t)node * 64 + lane] = acc - m - __logf(s);
}

// ---------------- launch ----------------

extern "C" void kernel_launch(void* const* d_in, const int* in_sizes, int n_in,
                              void* d_out, int out_size, void* d_ws, size_t ws_size,
                              hipStream_t stream) {
    const float* x  = (const float*)d_in[0];
    const int*   ei = (const int*)d_in[1];
    const float* W1 = (const float*)d_in[2];
    const float* b1 = (const float*)d_in[3];
    const float* W2 = (const float*)d_in[4];
    const float* b2 = (const float*)d_in[5];
    const float* W3 = (const float*)d_in[6];
    const float* b3 = (const float*)d_in[7];
    const int E = in_sizes[1] / 2;
    const int* src = ei;
    const int* dst = ei + E;
    const int N = NN;

    // workspace layout
    char* ws = (char*)d_ws;
    int*   deg    = (int*)ws;    ws += align_up((size_t)N * 4, 256);
    int*   cursor = (int*)ws;    ws += align_up((size_t)N * 4, 256);
    float* dinv   = (float*)ws;  ws += align_up((size_t)N * 4, 256);
    int*   rowptr = (int*)ws;    ws += align_up((size_t)(N + 1) * 4, 256);
    int*   esrc   = (int*)ws;    ws += align_up((size_t)E * 4, 256);
    float* enorm  = (float*)ws;  ws += align_up((size_t)E * 4, 256);
    float* bufA   = (float*)ws;  ws += (size_t)N * 256 * 4;  // gemm outputs (h1/h2/h3)
    float* bufB   = (float*)ws;  ws += (size_t)N * 256 * 4;  // activations (act1/act2)
    float* out    = (float*)d_out;

    hipMemsetAsync(deg, 0, (size_t)N * 4, stream);
    hipMemsetAsync(cursor, 0, (size_t)N * 4, stream);

    // CSR build (shared by all 3 layers)
    deg_count_kernel<<<(E + 255) / 256, 256, 0, stream>>>(dst, deg, E);
    dinv_kernel<<<(N + 255) / 256, 256, 0, stream>>>(deg, dinv, N);
    scan_kernel<<<1, 1024, 0, stream>>>(deg, rowptr, N);
    reorder_kernel<<<(E + 255) / 256, 256, 0, stream>>>(src, dst, rowptr, cursor, dinv, esrc, enorm, E);

    const int MB = (N + 63) / 64;       // GEMM row-blocks
    const int AB = (N + 3) / 4;         // agg blocks (4 nodes of 1 wave each)

    // ---- layer 1: 512 -> 256 ----
    gemm64_kernel<<<dim3(MB, 4), 256, 0, stream>>>(x, W1, bufA, N, 512, 256);
    agg_kernel<4, true><<<AB, 256, 0, stream>>>(bufA, rowptr, esrc, enorm, dinv, b1, bufB, N);

    // ---- layer 2: 256 -> 128 ----
    gemm64_kernel<<<dim3(MB, 2), 256, 0, stream>>>(bufB, W2, bufA, N, 256, 128);
    agg_kernel<2, true><<<AB, 256, 0, stream>>>(bufA, rowptr, esrc, enorm, dinv, b2, bufB, N);

    // ---- layer 3: 128 -> 64 ----
    gemm64_kernel<<<dim3(MB, 1), 256, 0, stream>>>(bufB, W3, bufA, N, 128, 64);
    agg_lsm_kernel<<<AB, 256, 0, stream>>>(bufA, rowptr, esrc, enorm, dinv, b3, out, N);
}

// Round 6
// 1211.796 us; speedup vs baseline: 8.6137x; 1.3943x over previous
//
#include <hip/hip_runtime.h>
#include <hip/hip_bf16.h>

#define NN 100000
#define MP 100096  // 782 * 128, padded row count for all [M,*] buffers we own

typedef unsigned short u16;
typedef __attribute__((ext_vector_type(8))) short bf16x8;
typedef __attribute__((ext_vector_type(4))) float f32x4;

static inline size_t align_up(size_t x, size_t a) { return (x + a - 1) & ~(a - 1); }

__device__ inline u16 f2b(float f) {  // RNE f32 -> bf16 (finite inputs)
    unsigned u = __float_as_uint(f);
    return (u16)((u + 0x7FFF + ((u >> 16) & 1)) >> 16);
}
__device__ inline float b2f(u16 u) { return __uint_as_float(((unsigned)u) << 16); }

// ---------------- CSR build ----------------

__global__ __launch_bounds__(256) void deg_count_kernel(const int* __restrict__ dst,
                                                        int* __restrict__ deg, int E) {
    int t = blockIdx.x * 256 + threadIdx.x;
    if (t < E) atomicAdd(&deg[dst[t]], 1);
}

__global__ __launch_bounds__(256) void dinv_kernel(const int* __restrict__ deg,
                                                   float* __restrict__ dinv, int n) {
    int t = blockIdx.x * 256 + threadIdx.x;
    if (t < n) dinv[t] = rsqrtf((float)deg[t] + 1.0f);
}

__global__ __launch_bounds__(1024) void scan_kernel(const int* __restrict__ deg,
                                                    int* __restrict__ rowptr, int n) {
    __shared__ int sums[1024];
    const int t = threadIdx.x;
    const int C = (n + 1023) >> 10;
    const int lo = t * C;
    const int hi = min(lo + C, n);
    int s = 0;
    for (int i = lo; i < hi; ++i) s += deg[i];
    sums[t] = s;
    __syncthreads();
    for (int d = 1; d < 1024; d <<= 1) {
        int v = (t >= d) ? sums[t - d] : 0;
        __syncthreads();
        sums[t] += v;
        __syncthreads();
    }
    int off = sums[t] - s;
    for (int i = lo; i < hi; ++i) { rowptr[i] = off; off += deg[i]; }
    if (hi == n) rowptr[n] = off;
}

__global__ __launch_bounds__(256) void reorder_kernel(const int* __restrict__ src,
        const int* __restrict__ dst, const int* __restrict__ rowptr,
        int* __restrict__ cursor, const float* __restrict__ dinv,
        int* __restrict__ esrc, float* __restrict__ enorm, int E) {
    int e = blockIdx.x * 256 + threadIdx.x;
    if (e >= E) return;
    int s = src[e], d = dst[e];
    int pos = rowptr[d] + atomicAdd(&cursor[d], 1);
    esrc[pos] = s;
    enorm[pos] = dinv[s] * dinv[d];
}

// ---------------- conversions ----------------

// fp32 -> bf16, 8 elems/thread, n8 = n/8 (exact)
__global__ __launch_bounds__(256) void cvt_kernel(const float* __restrict__ in,
                                                  u16* __restrict__ out, int n8) {
    int t = blockIdx.x * 256 + threadIdx.x;
    if (t >= n8) return;
    const float4* p = (const float4*)in + 2 * (size_t)t;
    float4 a = p[0], b = p[1];
    bf16x8 v;
    v[0] = (short)f2b(a.x); v[1] = (short)f2b(a.y); v[2] = (short)f2b(a.z); v[3] = (short)f2b(a.w);
    v[4] = (short)f2b(b.x); v[5] = (short)f2b(b.y); v[6] = (short)f2b(b.z); v[7] = (short)f2b(b.w);
    *(bf16x8*)(out + 8 * (size_t)t) = v;
}

// WT[n][k] = bf16(W[k][n]); t covers K*N outputs (write-coalesced)
__global__ __launch_bounds__(256) void transpose_kernel(const float* __restrict__ W,
                                                        u16* __restrict__ WT, int K, int N) {
    int t = blockIdx.x * 256 + threadIdx.x;
    if (t >= K * N) return;
    int n = t / K, k = t - n * K;
    WT[t] = f2b(W[(size_t)k * N + n]);
}

// ---------------- MFMA GEMM ----------------
// A[MP x K] bf16 rm, BT[(>=gridDim.y*128) x K] bf16 rm, C[MP x ldc] bf16 rm.
// BM=BN=128, BK=64, 256 threads = 4 waves (2x2, each 64x64).
// LDS tiles XOR-swizzled (byte ^= (row&7)<<4), swizzle applied on the GLOBAL
// source so global_load_lds' linear dest yields the swizzled layout (G4/T2).
__global__ __launch_bounds__(256) void gemm_mfma(const u16* __restrict__ A,
        const u16* __restrict__ BT, u16* __restrict__ C, int K, int ldc) {
    __shared__ char lds[32768];
    char* Al = lds;
    char* Bl = lds + 16384;
    const int tid = threadIdx.x;
    const int l = tid & 63;
    const int w = tid >> 6;
    const int wm = w >> 1, wn = w & 1;
    const long bm = (long)blockIdx.x * 128;
    const long bn = (long)blockIdx.y * 128;

    f32x4 acc[4][4];
    #pragma unroll
    for (int mi = 0; mi < 4; ++mi)
        #pragma unroll
        for (int ni = 0; ni < 4; ++ni)
            acc[mi][ni] = (f32x4){0.f, 0.f, 0.f, 0.f};

    const int srow = tid >> 3;          // 0..31: tile row per staging iter
    const int schunk = (tid & 7) << 4;  // byte-in-row 0..112

    for (int k0 = 0; k0 < K; k0 += 64) {
        __syncthreads();  // previous compute done before overwrite
        #pragma unroll
        for (int i = 0; i < 4; ++i) {
            const int row = i * 32 + srow;
            const int lb = schunk ^ ((row & 7) << 4);  // logical in-row byte (pre-swizzled src)
            const u16* ga = A + (bm + row) * K + k0 + (lb >> 1);
            const u16* gb = BT + (bn + row) * K + k0 + (lb >> 1);
            char* la = Al + i * 4096 + tid * 16;
            char* lbp = Bl + i * 4096 + tid * 16;
            __builtin_amdgcn_global_load_lds((const __attribute__((address_space(1))) void*)ga,
                                             (__attribute__((address_space(3))) void*)la, 16, 0, 0);
            __builtin_amdgcn_global_load_lds((const __attribute__((address_space(1))) void*)gb,
                                             (__attribute__((address_space(3))) void*)lbp, 16, 0, 0);
        }
        __syncthreads();  // waits vmcnt(0): staged data visible
        #pragma unroll
        for (int kk = 0; kk < 2; ++kk) {
            const int kbyte = kk * 64 + ((l >> 4) << 4);
            const int swz = (l & 7) << 4;  // (row&7)<<4 with row ≡ l (mod 8)
            bf16x8 af[4], bfr[4];
            #pragma unroll
            for (int mi = 0; mi < 4; ++mi) {
                const int row = wm * 64 + mi * 16 + (l & 15);
                af[mi] = *(const bf16x8*)(Al + row * 128 + (kbyte ^ swz));
            }
            #pragma unroll
            for (int ni = 0; ni < 4; ++ni) {
                const int row = wn * 64 + ni * 16 + (l & 15);
                bfr[ni] = *(const bf16x8*)(Bl + row * 128 + (kbyte ^ swz));
            }
            #pragma unroll
            for (int mi = 0; mi < 4; ++mi)
                #pragma unroll
                for (int ni = 0; ni < 4; ++ni)
                    acc[mi][ni] = __builtin_amdgcn_mfma_f32_16x16x32_bf16(
                        af[mi], bfr[ni], acc[mi][ni], 0, 0, 0);
        }
    }

    const long r0 = bm + wm * 64 + ((l >> 4) << 2);
    const long c0 = bn + wn * 64 + (l & 15);
    #pragma unroll
    for (int mi = 0; mi < 4; ++mi)
        #pragma unroll
        for (int r = 0; r < 4; ++r) {
            const long row = r0 + mi * 16 + r;
            #pragma unroll
            for (int ni = 0; ni < 4; ++ni)
                C[row * ldc + c0 + ni * 16] = f2b(acc[mi][ni][r]);
        }
}

// ---------------- aggregation (bf16 in, bf16 out) ----------------
// out[n] = relu( sum_e h[esrc[e]]*enorm[e] + h[n]*dinv[n]^2 + bias ), F = 64*VEC

template<int VEC, bool RELU>
__global__ __launch_bounds__(256) void agg_kernel(const u16* __restrict__ h,
        const int* __restrict__ rowptr, const int* __restrict__ esrc,
        const float* __restrict__ enorm, const float* __restrict__ dinv,
        const float* __restrict__ bias, u16* __restrict__ out, int N) {
    const int node = blockIdx.x * 4 + (threadIdx.x >> 6);
    if (node >= N) return;
    const int lane = threadIdx.x & 63;
    const int F = 64 * VEC;
    const float di = dinv[node];
    const float d2 = di * di;
    float acc[VEC];
    {
        const u16* hp = h + (size_t)node * F + lane * VEC;
        if constexpr (VEC == 4) {
            ushort4 v = *(const ushort4*)hp;
            float4 b = *(const float4*)(bias + lane * 4);
            acc[0] = b2f(v.x) * d2 + b.x; acc[1] = b2f(v.y) * d2 + b.y;
            acc[2] = b2f(v.z) * d2 + b.z; acc[3] = b2f(v.w) * d2 + b.w;
        } else {
            ushort2 v = *(const ushort2*)hp;
            float2 b = *(const float2*)(bias + lane * 2);
            acc[0] = b2f(v.x) * d2 + b.x; acc[1] = b2f(v.y) * d2 + b.y;
        }
    }
    const int e0 = rowptr[node], e1 = rowptr[node + 1];
    for (int e = e0; e < e1; ++e) {
        const int s = esrc[e];
        const float wgt = enorm[e];
        const u16* sp = h + (size_t)s * F + lane * VEC;
        if constexpr (VEC == 4) {
            ushort4 v = *(const ushort4*)sp;
            acc[0] += b2f(v.x) * wgt; acc[1] += b2f(v.y) * wgt;
            acc[2] += b2f(v.z) * wgt; acc[3] += b2f(v.w) * wgt;
        } else {
            ushort2 v = *(const ushort2*)sp;
            acc[0] += b2f(v.x) * wgt; acc[1] += b2f(v.y) * wgt;
        }
    }
    u16* op = out + (size_t)node * F + lane * VEC;
    if constexpr (VEC == 4) {
        ushort4 r;
        r.x = f2b(RELU ? fmaxf(acc[0], 0.f) : acc[0]);
        r.y = f2b(RELU ? fmaxf(acc[1], 0.f) : acc[1]);
        r.z = f2b(RELU ? fmaxf(acc[2], 0.f) : acc[2]);
        r.w = f2b(RELU ? fmaxf(acc[3], 0.f) : acc[3]);
        *(ushort4*)op = r;
    } else {
        ushort2 r;
        r.x = f2b(RELU ? fmaxf(acc[0], 0.f) : acc[0]);
        r.y = f2b(RELU ? fmaxf(acc[1], 0.f) : acc[1]);
        *(ushort2*)op = r;
    }
}

// final layer: h is [MP][128] bf16, logical F=64 (cols 0..63); fp32 out + log_softmax
__global__ __launch_bounds__(256) void agg_lsm_kernel(const u16* __restrict__ h,
        const int* __restrict__ rowptr, const int* __restrict__ esrc,
        const float* __restrict__ enorm, const float* __restrict__ dinv,
        const float* __restrict__ bias, float* __restrict__ out, int N) {
    const int node = blockIdx.x * 4 + (threadIdx.x >> 6);
    if (node >= N) return;
    const int lane = threadIdx.x & 63;
    const float di = dinv[node];
    float acc = b2f(h[(size_t)node * 128 + lane]) * di * di + bias[lane];
    const int e0 = rowptr[node], e1 = rowptr[node + 1];
    for (int e = e0; e < e1; ++e)
        acc += b2f(h[(size_t)esrc[e] * 128 + lane]) * enorm[e];
    float m = acc;
    #pragma unroll
    for (int o = 32; o; o >>= 1) m = fmaxf(m, __shfl_xor(m, o, 64));
    float ex = __expf(acc - m);
    float s = ex;
    #pragma unroll
    for (int o = 32; o; o >>= 1) s += __shfl_xor(s, o, 64);
    out[(size_t)node * 64 + lane] = acc - m - __logf(s);
}

// ---------------- launch ----------------

extern "C" void kernel_launch(void* const* d_in, const int* in_sizes, int n_in,
                              void* d_out, int out_size, void* d_ws, size_t ws_size,
                              hipStream_t stream) {
    const float* x  = (const float*)d_in[0];
    const int*   ei = (const int*)d_in[1];
    const float* W1 = (const float*)d_in[2];
    const float* b1 = (const float*)d_in[3];
    const float* W2 = (const float*)d_in[4];
    const float* b2 = (const float*)d_in[5];
    const float* W3 = (const float*)d_in[6];
    const float* b3 = (const float*)d_in[7];
    const int E = in_sizes[1] / 2;
    const int* src = ei;
    const int* dst = ei + E;
    const int N = NN;

    char* ws = (char*)d_ws;
    int*   deg    = (int*)ws;    ws += align_up((size_t)N * 4, 256);
    int*   cursor = (int*)ws;    ws += align_up((size_t)N * 4, 256);
    float* dinv   = (float*)ws;  ws += align_up((size_t)N * 4, 256);
    int*   rowptr = (int*)ws;    ws += align_up((size_t)(N + 1) * 4, 256);
    int*   esrc   = (int*)ws;    ws += align_up((size_t)E * 4, 256);
    float* enorm  = (float*)ws;  ws += align_up((size_t)E * 4, 256);
    u16*   wt1    = (u16*)ws;    ws += align_up((size_t)256 * 512 * 2, 256);
    u16*   wt2    = (u16*)ws;    ws += align_up((size_t)128 * 256 * 2, 256);
    u16*   wt3    = (u16*)ws;    ws += align_up((size_t)128 * 128 * 2, 256);  // rows 64.. stay garbage
    u16*   xb     = (u16*)ws;    ws += (size_t)MP * 512 * 2;  // later reused as h2b [MP][128]
    u16*   bufH   = (u16*)ws;    ws += (size_t)MP * 256 * 2;  // h1b; later h3b [MP][128]
    u16*   bufAct = (u16*)ws;    ws += (size_t)MP * 256 * 2;  // act1b; later act2b [MP][128]
    u16*   h2b  = xb;
    u16*   h3b  = bufH;
    float* out  = (float*)d_out;

    hipMemsetAsync(deg, 0, (size_t)N * 4, stream);
    hipMemsetAsync(cursor, 0, (size_t)N * 4, stream);

    deg_count_kernel<<<(E + 255) / 256, 256, 0, stream>>>(dst, deg, E);
    dinv_kernel<<<(N + 255) / 256, 256, 0, stream>>>(deg, dinv, N);
    scan_kernel<<<1, 1024, 0, stream>>>(deg, rowptr, N);
    reorder_kernel<<<(E + 255) / 256, 256, 0, stream>>>(src, dst, rowptr, cursor, dinv, esrc, enorm, E);

    // bf16 conversions
    cvt_kernel<<<(N * 512 / 8 + 255) / 256, 256, 0, stream>>>(x, xb, N * 512 / 8);
    transpose_kernel<<<(512 * 256 + 255) / 256, 256, 0, stream>>>(W1, wt1, 512, 256);
    transpose_kernel<<<(256 * 128 + 255) / 256, 256, 0, stream>>>(W2, wt2, 256, 128);
    transpose_kernel<<<(128 * 64 + 255) / 256, 256, 0, stream>>>(W3, wt3, 128, 64);

    const int GB = MP / 128;       // 782 row-blocks
    const int AB = (N + 3) / 4;    // 25000 agg blocks

    // ---- layer 1: 512 -> 256 ----
    gemm_mfma<<<dim3(GB, 2), 256, 0, stream>>>(xb, wt1, bufH, 512, 256);
    agg_kernel<4, true><<<AB, 256, 0, stream>>>(bufH, rowptr, esrc, enorm, dinv, b1, bufAct, N);

    // ---- layer 2: 256 -> 128 ----
    gemm_mfma<<<dim3(GB, 1), 256, 0, stream>>>(bufAct, wt2, h2b, 256, 128);
    agg_kernel<2, true><<<AB, 256, 0, stream>>>(h2b, rowptr, esrc, enorm, dinv, b2, bufAct, N);

    // ---- layer 3: 128 -> 64 (padded to 128 cols; cols 64.. are junk, unread) ----
    gemm_mfma<<<dim3(GB, 1), 256, 0, stream>>>(bufAct, wt3, h3b, 128, 128);
    agg_lsm_kernel<<<AB, 256, 0, stream>>>(h3b, rowptr, esrc, enorm, dinv, b3, out, N);
}

// Round 11
// 813.619 us; speedup vs baseline: 12.8291x; 1.4894x over previous
//
#include <hip/hip_runtime.h>
#include <hip/hip_bf16.h>

#define NN 100000
#define MP 100096  // 782 * 128, padded row count for all [M,*] buffers we own

typedef unsigned short u16;
typedef __attribute__((ext_vector_type(8))) short bf16x8;
typedef __attribute__((ext_vector_type(4))) float f32x4;

static inline size_t align_up(size_t x, size_t a) { return (x + a - 1) & ~(a - 1); }

__device__ inline u16 f2b(float f) {  // RNE f32 -> bf16 (finite inputs)
    unsigned u = __float_as_uint(f);
    return (u16)((u + 0x7FFF + ((u >> 16) & 1)) >> 16);
}
__device__ inline float b2f(u16 u) { return __uint_as_float(((unsigned)u) << 16); }

// ---------------- CSR build ----------------

__global__ __launch_bounds__(256) void deg_count_kernel(const int* __restrict__ dst,
                                                        int* __restrict__ deg, int E) {
    int t = blockIdx.x * 256 + threadIdx.x;
    if (t < E) atomicAdd(&deg[dst[t]], 1);
}

__global__ __launch_bounds__(256) void dinv_kernel(const int* __restrict__ deg,
                                                   float* __restrict__ dinv, int n) {
    int t = blockIdx.x * 256 + threadIdx.x;
    if (t < n) dinv[t] = rsqrtf((float)deg[t] + 1.0f);
}

// 3-phase parallel exclusive scan over deg[0..n), n % 4 == 0, n4 = n/4.
// phase1: per-block (256 thr x int4) sums -> partials[b]
__global__ __launch_bounds__(256) void scan_phase1(const int* __restrict__ deg,
                                                   int* __restrict__ partials, int n4) {
    __shared__ int red[256];
    const int t = threadIdx.x;
    const int g = blockIdx.x * 256 + t;
    int4 v = make_int4(0, 0, 0, 0);
    if (g < n4) v = ((const int4*)deg)[g];
    red[t] = v.x + v.y + v.z + v.w;
    __syncthreads();
    #pragma unroll
    for (int d = 128; d; d >>= 1) {
        if (t < d) red[t] += red[t + d];
        __syncthreads();
    }
    if (t == 0) partials[blockIdx.x] = red[0];
}

// phase2: single block scans partials[0..nb) (nb <= 128), writes rowptr[n] = total
__global__ __launch_bounds__(128) void scan_phase2(int* __restrict__ partials,
                                                   int* __restrict__ rowptr, int nb, int n) {
    __shared__ int ps[128];
    const int t = threadIdx.x;
    int v = (t < nb) ? partials[t] : 0;
    ps[t] = v;
    __syncthreads();
    #pragma unroll
    for (int d = 1; d < 128; d <<= 1) {
        int u = (t >= d) ? ps[t - d] : 0;
        __syncthreads();
        ps[t] += u;
        __syncthreads();
    }
    if (t < nb) partials[t] = ps[t] - v;   // exclusive prefix
    if (t == nb - 1) rowptr[n] = ps[t];    // total
}

// phase3: per-block exclusive scan + base, writes rowptr[0..n)
__global__ __launch_bounds__(256) void scan_phase3(const int* __restrict__ deg,
                                                   const int* __restrict__ partials,
                                                   int* __restrict__ rowptr, int n4) {
    __shared__ int ts[256];
    const int t = threadIdx.x;
    const int g = blockIdx.x * 256 + t;
    int4 v = make_int4(0, 0, 0, 0);
    if (g < n4) v = ((const int4*)deg)[g];
    const int s0 = v.x, s1 = s0 + v.y, s2 = s1 + v.z, s3 = s2 + v.w;
    ts[t] = s3;
    __syncthreads();
    #pragma unroll
    for (int d = 1; d < 256; d <<= 1) {
        int u = (t >= d) ? ts[t - d] : 0;
        __syncthreads();
        ts[t] += u;
        __syncthreads();
    }
    if (g < n4) {
        const int base = partials[blockIdx.x] + ts[t] - s3;
        int4 r;
        r.x = base; r.y = base + s0; r.z = base + s1; r.w = base + s2;
        ((int4*)rowptr)[g] = r;
    }
}

// scatter edges into dst-sorted order as (src, norm) 8-byte records
__global__ __launch_bounds__(256) void reorder_kernel(const int* __restrict__ src,
        const int* __restrict__ dst, const int* __restrict__ rowptr,
        int* __restrict__ cursor, const float* __restrict__ dinv,
        int2* __restrict__ erec, int E) {
    int e = blockIdx.x * 256 + threadIdx.x;
    if (e >= E) return;
    int s = src[e], d = dst[e];
    int pos = rowptr[d] + atomicAdd(&cursor[d], 1);
    erec[pos] = make_int2(s, __float_as_int(dinv[s] * dinv[d]));
}

// ---------------- conversions ----------------

__global__ __launch_bounds__(256) void cvt_kernel(const float* __restrict__ in,
                                                  u16* __restrict__ out, int n8) {
    int t = blockIdx.x * 256 + threadIdx.x;
    if (t >= n8) return;
    const float4* p = (const float4*)in + 2 * (size_t)t;
    float4 a = p[0], b = p[1];
    bf16x8 v;
    v[0] = (short)f2b(a.x); v[1] = (short)f2b(a.y); v[2] = (short)f2b(a.z); v[3] = (short)f2b(a.w);
    v[4] = (short)f2b(b.x); v[5] = (short)f2b(b.y); v[6] = (short)f2b(b.z); v[7] = (short)f2b(b.w);
    *(bf16x8*)(out + 8 * (size_t)t) = v;
}

__global__ __launch_bounds__(256) void transpose_kernel(const float* __restrict__ W,
                                                        u16* __restrict__ WT, int K, int N) {
    int t = blockIdx.x * 256 + threadIdx.x;
    if (t >= K * N) return;
    int n = t / K, k = t - n * K;
    WT[t] = f2b(W[(size_t)k * N + n]);
}

// ---------------- MFMA GEMM (unchanged from R6, measured good) ----------------
__global__ __launch_bounds__(256) void gemm_mfma(const u16* __restrict__ A,
        const u16* __restrict__ BT, u16* __restrict__ C, int K, int ldc) {
    __shared__ char lds[32768];
    char* Al = lds;
    char* Bl = lds + 16384;
    const int tid = threadIdx.x;
    const int l = tid & 63;
    const int w = tid >> 6;
    const int wm = w >> 1, wn = w & 1;
    const long bm = (long)blockIdx.x * 128;
    const long bn = (long)blockIdx.y * 128;

    f32x4 acc[4][4];
    #pragma unroll
    for (int mi = 0; mi < 4; ++mi)
        #pragma unroll
        for (int ni = 0; ni < 4; ++ni)
            acc[mi][ni] = (f32x4){0.f, 0.f, 0.f, 0.f};

    const int srow = tid >> 3;
    const int schunk = (tid & 7) << 4;

    for (int k0 = 0; k0 < K; k0 += 64) {
        __syncthreads();
        #pragma unroll
        for (int i = 0; i < 4; ++i) {
            const int row = i * 32 + srow;
            const int lb = schunk ^ ((row & 7) << 4);
            const u16* ga = A + (bm + row) * K + k0 + (lb >> 1);
            const u16* gb = BT + (bn + row) * K + k0 + (lb >> 1);
            char* la = Al + i * 4096 + tid * 16;
            char* lbp = Bl + i * 4096 + tid * 16;
            __builtin_amdgcn_global_load_lds((const __attribute__((address_space(1))) void*)ga,
                                             (__attribute__((address_space(3))) void*)la, 16, 0, 0);
            __builtin_amdgcn_global_load_lds((const __attribute__((address_space(1))) void*)gb,
                                             (__attribute__((address_space(3))) void*)lbp, 16, 0, 0);
        }
        __syncthreads();
        #pragma unroll
        for (int kk = 0; kk < 2; ++kk) {
            const int kbyte = kk * 64 + ((l >> 4) << 4);
            const int swz = (l & 7) << 4;
            bf16x8 af[4], bfr[4];
            #pragma unroll
            for (int mi = 0; mi < 4; ++mi) {
                const int row = wm * 64 + mi * 16 + (l & 15);
                af[mi] = *(const bf16x8*)(Al + row * 128 + (kbyte ^ swz));
            }
            #pragma unroll
            for (int ni = 0; ni < 4; ++ni) {
                const int row = wn * 64 + ni * 16 + (l & 15);
                bfr[ni] = *(const bf16x8*)(Bl + row * 128 + (kbyte ^ swz));
            }
            #pragma unroll
            for (int mi = 0; mi < 4; ++mi)
                #pragma unroll
                for (int ni = 0; ni < 4; ++ni)
                    acc[mi][ni] = __builtin_amdgcn_mfma_f32_16x16x32_bf16(
                        af[mi], bfr[ni], acc[mi][ni], 0, 0, 0);
        }
    }

    const long r0 = bm + wm * 64 + ((l >> 4) << 2);
    const long c0 = bn + wn * 64 + (l & 15);
    #pragma unroll
    for (int mi = 0; mi < 4; ++mi)
        #pragma unroll
        for (int r = 0; r < 4; ++r) {
            const long row = r0 + mi * 16 + r;
            #pragma unroll
            for (int ni = 0; ni < 4; ++ni)
                C[row * ldc + c0 + ni * 16] = f2b(acc[mi][ni][r]);
        }
}

// ---------------- aggregation: unroll-4 pipelined gather ----------------
// out[n] = relu( sum_e h[rec.src]*rec.norm + h[n]*dinv[n]^2 + bias ), F = 64*VEC

template<int VEC, bool RELU>
__global__ __launch_bounds__(256) void agg_kernel(const u16* __restrict__ h,
        const int* __restrict__ rowptr, const int2* __restrict__ erec,
        const float* __restrict__ dinv, const float* __restrict__ bias,
        u16* __restrict__ out, int N) {
    const int node = blockIdx.x * 4 + (threadIdx.x >> 6);
    if (node >= N) return;
    const int lane = threadIdx.x & 63;
    const int F = 64 * VEC;
    const float di = dinv[node];
    const float d2 = di * di;
    float acc[VEC];
    {
        const u16* hp = h + (size_t)node * F + lane * VEC;
        if constexpr (VEC == 4) {
            ushort4 v = *(const ushort4*)hp;
            float4 b = *(const float4*)(bias + lane * 4);
            acc[0] = b2f(v.x) * d2 + b.x; acc[1] = b2f(v.y) * d2 + b.y;
            acc[2] = b2f(v.z) * d2 + b.z; acc[3] = b2f(v.w) * d2 + b.w;
        } else {
            ushort2 v = *(const ushort2*)hp;
            float2 b = *(const float2*)(bias + lane * 2);
            acc[0] = b2f(v.x) * d2 + b.x; acc[1] = b2f(v.y) * d2 + b.y;
        }
    }
    const int e0 = rowptr[node], e1 = rowptr[node + 1];
    int e = e0;
    for (; e + 4 <= e1; e += 4) {
        int2 r0 = erec[e], r1 = erec[e + 1], r2 = erec[e + 2], r3 = erec[e + 3];
        const u16* p0 = h + (size_t)r0.x * F + lane * VEC;
        const u16* p1 = h + (size_t)r1.x * F + lane * VEC;
        const u16* p2 = h + (size_t)r2.x * F + lane * VEC;
        const u16* p3 = h + (size_t)r3.x * F + lane * VEC;
        const float w0 = __int_as_float(r0.y), w1 = __int_as_float(r1.y);
        const float w2 = __int_as_float(r2.y), w3 = __int_as_float(r3.y);
        if constexpr (VEC == 4) {
            ushort4 v0 = *(const ushort4*)p0;
            ushort4 v1 = *(const ushort4*)p1;
            ushort4 v2 = *(const ushort4*)p2;
            ushort4 v3 = *(const ushort4*)p3;
            acc[0] += b2f(v0.x) * w0; acc[1] += b2f(v0.y) * w0; acc[2] += b2f(v0.z) * w0; acc[3] += b2f(v0.w) * w0;
            acc[0] += b2f(v1.x) * w1; acc[1] += b2f(v1.y) * w1; acc[2] += b2f(v1.z) * w1; acc[3] += b2f(v1.w) * w1;
            acc[0] += b2f(v2.x) * w2; acc[1] += b2f(v2.y) * w2; acc[2] += b2f(v2.z) * w2; acc[3] += b2f(v2.w) * w2;
            acc[0] += b2f(v3.x) * w3; acc[1] += b2f(v3.y) * w3; acc[2] += b2f(v3.z) * w3; acc[3] += b2f(v3.w) * w3;
        } else {
            ushort2 v0 = *(const ushort2*)p0;
            ushort2 v1 = *(const ushort2*)p1;
            ushort2 v2 = *(const ushort2*)p2;
            ushort2 v3 = *(const ushort2*)p3;
            acc[0] += b2f(v0.x) * w0; acc[1] += b2f(v0.y) * w0;
            acc[0] += b2f(v1.x) * w1; acc[1] += b2f(v1.y) * w1;
            acc[0] += b2f(v2.x) * w2; acc[1] += b2f(v2.y) * w2;
            acc[0] += b2f(v3.x) * w3; acc[1] += b2f(v3.y) * w3;
        }
    }
    for (; e < e1; ++e) {
        int2 r = erec[e];
        const float wgt = __int_as_float(r.y);
        const u16* sp = h + (size_t)r.x * F + lane * VEC;
        if constexpr (VEC == 4) {
            ushort4 v = *(const ushort4*)sp;
            acc[0] += b2f(v.x) * wgt; acc[1] += b2f(v.y) * wgt;
            acc[2] += b2f(v.z) * wgt; acc[3] += b2f(v.w) * wgt;
        } else {
            ushort2 v = *(const ushort2*)sp;
            acc[0] += b2f(v.x) * wgt; acc[1] += b2f(v.y) * wgt;
        }
    }
    u16* op = out + (size_t)node * F + lane * VEC;
    if constexpr (VEC == 4) {
        ushort4 r;
        r.x = f2b(RELU ? fmaxf(acc[0], 0.f) : acc[0]);
        r.y = f2b(RELU ? fmaxf(acc[1], 0.f) : acc[1]);
        r.z = f2b(RELU ? fmaxf(acc[2], 0.f) : acc[2]);
        r.w = f2b(RELU ? fmaxf(acc[3], 0.f) : acc[3]);
        *(ushort4*)op = r;
    } else {
        ushort2 r;
        r.x = f2b(RELU ? fmaxf(acc[0], 0.f) : acc[0]);
        r.y = f2b(RELU ? fmaxf(acc[1], 0.f) : acc[1]);
        *(ushort2*)op = r;
    }
}

// final layer: h is [MP][128] bf16, logical F=64; fused log_softmax, fp32 out
__global__ __launch_bounds__(256) void agg_lsm_kernel(const u16* __restrict__ h,
        const int* __restrict__ rowptr, const int2* __restrict__ erec,
        const float* __restrict__ dinv, const float* __restrict__ bias,
        float* __restrict__ out, int N) {
    const int node = blockIdx.x * 4 + (threadIdx.x >> 6);
    if (node >= N) return;
    const int lane = threadIdx.x & 63;
    const float di = dinv[node];
    float acc = b2f(h[(size_t)node * 128 + lane]) * di * di + bias[lane];
    const int e0 = rowptr[node], e1 = rowptr[node + 1];
    int e = e0;
    for (; e + 4 <= e1; e += 4) {
        int2 r0 = erec[e], r1 = erec[e + 1], r2 = erec[e + 2], r3 = erec[e + 3];
        float v0 = b2f(h[(size_t)r0.x * 128 + lane]);
        float v1 = b2f(h[(size_t)r1.x * 128 + lane]);
        float v2 = b2f(h[(size_t)r2.x * 128 + lane]);
        float v3 = b2f(h[(size_t)r3.x * 128 + lane]);
        acc += v0 * __int_as_float(r0.y);
        acc += v1 * __int_as_float(r1.y);
        acc += v2 * __int_as_float(r2.y);
        acc += v3 * __int_as_float(r3.y);
    }
    for (; e < e1; ++e) {
        int2 r = erec[e];
        acc += b2f(h[(size_t)r.x * 128 + lane]) * __int_as_float(r.y);
    }
    float m = acc;
    #pragma unroll
    for (int o = 32; o; o >>= 1) m = fmaxf(m, __shfl_xor(m, o, 64));
    float ex = __expf(acc - m);
    float s = ex;
    #pragma unroll
    for (int o = 32; o; o >>= 1) s += __shfl_xor(s, o, 64);
    out[(size_t)node * 64 + lane] = acc - m - __logf(s);
}

// ---------------- launch ----------------

extern "C" void kernel_launch(void* const* d_in, const int* in_sizes, int n_in,
                              void* d_out, int out_size, void* d_ws, size_t ws_size,
                              hipStream_t stream) {
    const float* x  = (const float*)d_in[0];
    const int*   ei = (const int*)d_in[1];
    const float* W1 = (const float*)d_in[2];
    const float* b1 = (const float*)d_in[3];
    const float* W2 = (const float*)d_in[4];
    const float* b2 = (const float*)d_in[5];
    const float* W3 = (const float*)d_in[6];
    const float* b3 = (const float*)d_in[7];
    const int E = in_sizes[1] / 2;
    const int* src = ei;
    const int* dst = ei + E;
    const int N = NN;
    const int N4 = N / 4;                  // 25000 (N % 4 == 0)
    const int NB = (N4 + 255) / 256;       // 98 scan blocks

    char* ws = (char*)d_ws;
    int*   deg      = (int*)ws;    ws += align_up((size_t)N * 4, 256);
    int*   cursor   = (int*)ws;    ws += align_up((size_t)N * 4, 256);
    float* dinv     = (float*)ws;  ws += align_up((size_t)N * 4, 256);
    int*   rowptr   = (int*)ws;    ws += align_up((size_t)(N + 1) * 4, 256);
    int*   partials = (int*)ws;    ws += align_up((size_t)128 * 4, 256);
    int2*  erec     = (int2*)ws;   ws += align_up((size_t)E * 8, 256);
    u16*   wt1      = (u16*)ws;    ws += align_up((size_t)256 * 512 * 2, 256);
    u16*   wt2      = (u16*)ws;    ws += align_up((size_t)128 * 256 * 2, 256);
    u16*   wt3      = (u16*)ws;    ws += align_up((size_t)128 * 128 * 2, 256);
    u16*   xb       = (u16*)ws;    ws += (size_t)MP * 512 * 2;  // later reused as h2b
    u16*   bufH     = (u16*)ws;    ws += (size_t)MP * 256 * 2;  // h1b; later h3b
    u16*   bufAct   = (u16*)ws;    ws += (size_t)MP * 256 * 2;  // act1b / act2b
    u16*   h2b  = xb;
    u16*   h3b  = bufH;
    float* out  = (float*)d_out;

    hipMemsetAsync(deg, 0, (size_t)N * 4, stream);
    hipMemsetAsync(cursor, 0, (size_t)N * 4, stream);

    deg_count_kernel<<<(E + 255) / 256, 256, 0, stream>>>(dst, deg, E);
    dinv_kernel<<<(N + 255) / 256, 256, 0, stream>>>(deg, dinv, N);
    scan_phase1<<<NB, 256, 0, stream>>>(deg, partials, N4);
    scan_phase2<<<1, 128, 0, stream>>>(partials, rowptr, NB, N);
    scan_phase3<<<NB, 256, 0, stream>>>(deg, partials, rowptr, N4);
    reorder_kernel<<<(E + 255) / 256, 256, 0, stream>>>(src, dst, rowptr, cursor, dinv, erec, E);

    cvt_kernel<<<(N * 512 / 8 + 255) / 256, 256, 0, stream>>>(x, xb, N * 512 / 8);
    transpose_kernel<<<(512 * 256 + 255) / 256, 256, 0, stream>>>(W1, wt1, 512, 256);
    transpose_kernel<<<(256 * 128 + 255) / 256, 256, 0, stream>>>(W2, wt2, 256, 128);
    transpose_kernel<<<(128 * 64 + 255) / 256, 256, 0, stream>>>(W3, wt3, 128, 64);

    const int GB = MP / 128;
    const int AB = (N + 3) / 4;

    // ---- layer 1: 512 -> 256 ----
    gemm_mfma<<<dim3(GB, 2), 256, 0, stream>>>(xb, wt1, bufH, 512, 256);
    agg_kernel<4, true><<<AB, 256, 0, stream>>>(bufH, rowptr, erec, dinv, b1, bufAct, N);

    // ---- layer 2: 256 -> 128 ----
    gemm_mfma<<<dim3(GB, 1), 256, 0, stream>>>(bufAct, wt2, h2b, 256, 128);
    agg_kernel<2, true><<<AB, 256, 0, stream>>>(h2b, rowptr, erec, dinv, b2, bufAct, N);

    // ---- layer 3: 128 -> 64 (padded to 128 cols) ----
    gemm_mfma<<<dim3(GB, 1), 256, 0, stream>>>(bufAct, wt3, h3b, 128, 128);
    agg_lsm_kernel<<<AB, 256, 0, stream>>>(h3b, rowptr, erec, dinv, b3, out, N);
}

// Round 12
// 773.591 us; speedup vs baseline: 13.4929x; 1.0517x over previous
//
#include <hip/hip_runtime.h>
#include <hip/hip_bf16.h>

#define NN 100000
#define MP 100096  // 782 * 128, padded row count for all [M,*] buffers we own

typedef unsigned short u16;
typedef __attribute__((ext_vector_type(8))) short bf16x8;
typedef __attribute__((ext_vector_type(4))) float f32x4;

static inline size_t align_up(size_t x, size_t a) { return (x + a - 1) & ~(a - 1); }

__device__ inline u16 f2b(float f) {  // RNE f32 -> bf16 (finite inputs)
    unsigned u = __float_as_uint(f);
    return (u16)((u + 0x7FFF + ((u >> 16) & 1)) >> 16);
}
__device__ inline float b2f(u16 u) { return __uint_as_float(((unsigned)u) << 16); }

// ---------------- CSR build ----------------

__global__ __launch_bounds__(256) void deg_count_kernel(const int* __restrict__ dst,
                                                        int* __restrict__ deg, int E) {
    int t = blockIdx.x * 256 + threadIdx.x;
    if (t < E) atomicAdd(&deg[dst[t]], 1);
}

__global__ __launch_bounds__(256) void dinv_kernel(const int* __restrict__ deg,
                                                   float* __restrict__ dinv, int n) {
    int t = blockIdx.x * 256 + threadIdx.x;
    if (t < n) dinv[t] = rsqrtf((float)deg[t] + 1.0f);
}

// 3-phase parallel exclusive scan over deg[0..n), n % 4 == 0, n4 = n/4.
__global__ __launch_bounds__(256) void scan_phase1(const int* __restrict__ deg,
                                                   int* __restrict__ partials, int n4) {
    __shared__ int red[256];
    const int t = threadIdx.x;
    const int g = blockIdx.x * 256 + t;
    int4 v = make_int4(0, 0, 0, 0);
    if (g < n4) v = ((const int4*)deg)[g];
    red[t] = v.x + v.y + v.z + v.w;
    __syncthreads();
    #pragma unroll
    for (int d = 128; d; d >>= 1) {
        if (t < d) red[t] += red[t + d];
        __syncthreads();
    }
    if (t == 0) partials[blockIdx.x] = red[0];
}

__global__ __launch_bounds__(128) void scan_phase2(int* __restrict__ partials,
                                                   int* __restrict__ rowptr, int nb, int n) {
    __shared__ int ps[128];
    const int t = threadIdx.x;
    int v = (t < nb) ? partials[t] : 0;
    ps[t] = v;
    __syncthreads();
    #pragma unroll
    for (int d = 1; d < 128; d <<= 1) {
        int u = (t >= d) ? ps[t - d] : 0;
        __syncthreads();
        ps[t] += u;
        __syncthreads();
    }
    if (t < nb) partials[t] = ps[t] - v;   // exclusive prefix
    if (t == nb - 1) rowptr[n] = ps[t];    // total
}

__global__ __launch_bounds__(256) void scan_phase3(const int* __restrict__ deg,
                                                   const int* __restrict__ partials,
                                                   int* __restrict__ rowptr, int n4) {
    __shared__ int ts[256];
    const int t = threadIdx.x;
    const int g = blockIdx.x * 256 + t;
    int4 v = make_int4(0, 0, 0, 0);
    if (g < n4) v = ((const int4*)deg)[g];
    const int s0 = v.x, s1 = s0 + v.y, s2 = s1 + v.z, s3 = s2 + v.w;
    ts[t] = s3;
    __syncthreads();
    #pragma unroll
    for (int d = 1; d < 256; d <<= 1) {
        int u = (t >= d) ? ts[t - d] : 0;
        __syncthreads();
        ts[t] += u;
        __syncthreads();
    }
    if (g < n4) {
        const int base = partials[blockIdx.x] + ts[t] - s3;
        int4 r;
        r.x = base; r.y = base + s0; r.z = base + s1; r.w = base + s2;
        ((int4*)rowptr)[g] = r;
    }
}

// scatter edges into dst-sorted order as (src, norm) 8-byte records
__global__ __launch_bounds__(256) void reorder_kernel(const int* __restrict__ src,
        const int* __restrict__ dst, const int* __restrict__ rowptr,
        int* __restrict__ cursor, const float* __restrict__ dinv,
        int2* __restrict__ erec, int E) {
    int e = blockIdx.x * 256 + threadIdx.x;
    if (e >= E) return;
    int s = src[e], d = dst[e];
    int pos = rowptr[d] + atomicAdd(&cursor[d], 1);
    erec[pos] = make_int2(s, __float_as_int(dinv[s] * dinv[d]));
}

// ---------------- weight transpose+convert ----------------

__global__ __launch_bounds__(256) void transpose_kernel(const float* __restrict__ W,
                                                        u16* __restrict__ WT, int K, int N) {
    int t = blockIdx.x * 256 + threadIdx.x;
    if (t >= K * N) return;
    int n = t / K, k = t - n * K;
    WT[t] = f2b(W[(size_t)k * N + n]);
}

// ---------------- MFMA GEMM, bf16 A (layers 2,3) ----------------
__global__ __launch_bounds__(256) void gemm_mfma(const u16* __restrict__ A,
        const u16* __restrict__ BT, u16* __restrict__ C, int K, int ldc) {
    __shared__ char lds[32768];
    char* Al = lds;
    char* Bl = lds + 16384;
    const int tid = threadIdx.x;
    const int l = tid & 63;
    const int w = tid >> 6;
    const int wm = w >> 1, wn = w & 1;
    const long bm = (long)blockIdx.x * 128;
    const long bn = (long)blockIdx.y * 128;

    f32x4 acc[4][4];
    #pragma unroll
    for (int mi = 0; mi < 4; ++mi)
        #pragma unroll
        for (int ni = 0; ni < 4; ++ni)
            acc[mi][ni] = (f32x4){0.f, 0.f, 0.f, 0.f};

    const int srow = tid >> 3;
    const int schunk = (tid & 7) << 4;

    for (int k0 = 0; k0 < K; k0 += 64) {
        __syncthreads();
        #pragma unroll
        for (int i = 0; i < 4; ++i) {
            const int row = i * 32 + srow;
            const int lb = schunk ^ ((row & 7) << 4);
            const u16* ga = A + (bm + row) * K + k0 + (lb >> 1);
            const u16* gb = BT + (bn + row) * K + k0 + (lb >> 1);
            char* la = Al + i * 4096 + tid * 16;
            char* lbp = Bl + i * 4096 + tid * 16;
            __builtin_amdgcn_global_load_lds((const __attribute__((address_space(1))) void*)ga,
                                             (__attribute__((address_space(3))) void*)la, 16, 0, 0);
            __builtin_amdgcn_global_load_lds((const __attribute__((address_space(1))) void*)gb,
                                             (__attribute__((address_space(3))) void*)lbp, 16, 0, 0);
        }
        __syncthreads();
        #pragma unroll
        for (int kk = 0; kk < 2; ++kk) {
            const int kbyte = kk * 64 + ((l >> 4) << 4);
            const int swz = (l & 7) << 4;
            bf16x8 af[4], bfr[4];
            #pragma unroll
            for (int mi = 0; mi < 4; ++mi) {
                const int row = wm * 64 + mi * 16 + (l & 15);
                af[mi] = *(const bf16x8*)(Al + row * 128 + (kbyte ^ swz));
            }
            #pragma unroll
            for (int ni = 0; ni < 4; ++ni) {
                const int row = wn * 64 + ni * 16 + (l & 15);
                bfr[ni] = *(const bf16x8*)(Bl + row * 128 + (kbyte ^ swz));
            }
            #pragma unroll
            for (int mi = 0; mi < 4; ++mi)
                #pragma unroll
                for (int ni = 0; ni < 4; ++ni)
                    acc[mi][ni] = __builtin_amdgcn_mfma_f32_16x16x32_bf16(
                        af[mi], bfr[ni], acc[mi][ni], 0, 0, 0);
        }
    }

    const long r0 = bm + wm * 64 + ((l >> 4) << 2);
    const long c0 = bn + wn * 64 + (l & 15);
    #pragma unroll
    for (int mi = 0; mi < 4; ++mi)
        #pragma unroll
        for (int r = 0; r < 4; ++r) {
            const long row = r0 + mi * 16 + r;
            #pragma unroll
            for (int ni = 0; ni < 4; ++ni)
                C[row * ldc + c0 + ni * 16] = f2b(acc[mi][ni][r]);
        }
}

// ---------------- MFMA GEMM, fp32 A fused-convert (layer 1) ----------------
// A32[N x K] fp32; converts to bf16 in-register during staging (bit-identical
// to cvt_kernel+gemm_mfma). A reg-staged with swizzled ds_write; B via
// global_load_lds with pre-swizzled source (both-sides rule kept per path).
__global__ __launch_bounds__(256) void gemm_mfma_f32a(const float* __restrict__ A32,
        const u16* __restrict__ BT, u16* __restrict__ C, int K, int ldc) {
    __shared__ char lds[32768];
    char* Al = lds;
    char* Bl = lds + 16384;
    const int tid = threadIdx.x;
    const int l = tid & 63;
    const int w = tid >> 6;
    const int wm = w >> 1, wn = w & 1;
    const long bm = (long)blockIdx.x * 128;
    const long bn = (long)blockIdx.y * 128;

    f32x4 acc[4][4];
    #pragma unroll
    for (int mi = 0; mi < 4; ++mi)
        #pragma unroll
        for (int ni = 0; ni < 4; ++ni)
            acc[mi][ni] = (f32x4){0.f, 0.f, 0.f, 0.f};

    const int srow = tid >> 3;          // 0..31
    const int schunk = (tid & 7) << 4;  // logical bf16 byte-in-row 0..112

    for (int k0 = 0; k0 < K; k0 += 64) {
        __syncthreads();
        // B: DMA to LDS first (overlaps A's register loads)
        #pragma unroll
        for (int i = 0; i < 4; ++i) {
            const int row = i * 32 + srow;
            const int lb = schunk ^ ((row & 7) << 4);
            const u16* gb = BT + (bn + row) * K + k0 + (lb >> 1);
            char* lbp = Bl + i * 4096 + tid * 16;
            __builtin_amdgcn_global_load_lds((const __attribute__((address_space(1))) void*)gb,
                                             (__attribute__((address_space(3))) void*)lbp, 16, 0, 0);
        }
        // A: fp32 -> regs -> bf16 -> swizzled ds_write
        float4 a0[4], a1[4];
        #pragma unroll
        for (int i = 0; i < 4; ++i) {
            const int row = i * 32 + srow;
            const long ar = (bm + row < NN) ? (bm + row) : (NN - 1);  // clamp: no OOB
            const float* ga = A32 + ar * K + k0 + (schunk >> 1);
            a0[i] = *(const float4*)ga;
            a1[i] = *(const float4*)(ga + 4);
        }
        #pragma unroll
        for (int i = 0; i < 4; ++i) {
            const int row = i * 32 + srow;
            bf16x8 v;
            v[0] = (short)f2b(a0[i].x); v[1] = (short)f2b(a0[i].y);
            v[2] = (short)f2b(a0[i].z); v[3] = (short)f2b(a0[i].w);
            v[4] = (short)f2b(a1[i].x); v[5] = (short)f2b(a1[i].y);
            v[6] = (short)f2b(a1[i].z); v[7] = (short)f2b(a1[i].w);
            *(bf16x8*)(Al + row * 128 + (schunk ^ ((row & 7) << 4))) = v;
        }
        __syncthreads();
        #pragma unroll
        for (int kk = 0; kk < 2; ++kk) {
            const int kbyte = kk * 64 + ((l >> 4) << 4);
            const int swz = (l & 7) << 4;
            bf16x8 af[4], bfr[4];
            #pragma unroll
            for (int mi = 0; mi < 4; ++mi) {
                const int row = wm * 64 + mi * 16 + (l & 15);
                af[mi] = *(const bf16x8*)(Al + row * 128 + (kbyte ^ swz));
            }
            #pragma unroll
            for (int ni = 0; ni < 4; ++ni) {
                const int row = wn * 64 + ni * 16 + (l & 15);
                bfr[ni] = *(const bf16x8*)(Bl + row * 128 + (kbyte ^ swz));
            }
            #pragma unroll
            for (int mi = 0; mi < 4; ++mi)
                #pragma unroll
                for (int ni = 0; ni < 4; ++ni)
                    acc[mi][ni] = __builtin_amdgcn_mfma_f32_16x16x32_bf16(
                        af[mi], bfr[ni], acc[mi][ni], 0, 0, 0);
        }
    }

    const long r0 = bm + wm * 64 + ((l >> 4) << 2);
    const long c0 = bn + wn * 64 + (l & 15);
    #pragma unroll
    for (int mi = 0; mi < 4; ++mi)
        #pragma unroll
        for (int r = 0; r < 4; ++r) {
            const long row = r0 + mi * 16 + r;
            #pragma unroll
            for (int ni = 0; ni < 4; ++ni)
                C[row * ldc + c0 + ni * 16] = f2b(acc[mi][ni][r]);
        }
}

// ---------------- aggregation: unroll-8 pipelined gather ----------------
// out[n] = relu( sum_e h[rec.src]*rec.norm + h[n]*dinv[n]^2 + bias ), F = 64*VEC

template<int VEC, bool RELU>
__global__ __launch_bounds__(256) void agg_kernel(const u16* __restrict__ h,
        const int* __restrict__ rowptr, const int2* __restrict__ erec,
        const float* __restrict__ dinv, const float* __restrict__ bias,
        u16* __restrict__ out, int N) {
    const int node = blockIdx.x * 4 + (threadIdx.x >> 6);
    if (node >= N) return;
    const int lane = threadIdx.x & 63;
    const int F = 64 * VEC;
    const float di = dinv[node];
    const float d2 = di * di;
    float acc[VEC];
    {
        const u16* hp = h + (size_t)node * F + lane * VEC;
        if constexpr (VEC == 4) {
            ushort4 v = *(const ushort4*)hp;
            float4 b = *(const float4*)(bias + lane * 4);
            acc[0] = b2f(v.x) * d2 + b.x; acc[1] = b2f(v.y) * d2 + b.y;
            acc[2] = b2f(v.z) * d2 + b.z; acc[3] = b2f(v.w) * d2 + b.w;
        } else {
            ushort2 v = *(const ushort2*)hp;
            float2 b = *(const float2*)(bias + lane * 2);
            acc[0] = b2f(v.x) * d2 + b.x; acc[1] = b2f(v.y) * d2 + b.y;
        }
    }
    const int e0 = rowptr[node], e1 = rowptr[node + 1];
    int e = e0;
    for (; e + 8 <= e1; e += 8) {
        int2 r[8];
        #pragma unroll
        for (int j = 0; j < 8; ++j) r[j] = erec[e + j];
        if constexpr (VEC == 4) {
            ushort4 v[8];
            #pragma unroll
            for (int j = 0; j < 8; ++j)
                v[j] = *(const ushort4*)(h + (size_t)r[j].x * F + lane * 4);
            #pragma unroll
            for (int j = 0; j < 8; ++j) {
                const float wj = __int_as_float(r[j].y);
                acc[0] += b2f(v[j].x) * wj; acc[1] += b2f(v[j].y) * wj;
                acc[2] += b2f(v[j].z) * wj; acc[3] += b2f(v[j].w) * wj;
            }
        } else {
            ushort2 v[8];
            #pragma unroll
            for (int j = 0; j < 8; ++j)
                v[j] = *(const ushort2*)(h + (size_t)r[j].x * F + lane * 2);
            #pragma unroll
            for (int j = 0; j < 8; ++j) {
                const float wj = __int_as_float(r[j].y);
                acc[0] += b2f(v[j].x) * wj; acc[1] += b2f(v[j].y) * wj;
            }
        }
    }
    for (; e + 4 <= e1; e += 4) {
        int2 r[4];
        #pragma unroll
        for (int j = 0; j < 4; ++j) r[j] = erec[e + j];
        if constexpr (VEC == 4) {
            ushort4 v[4];
            #pragma unroll
            for (int j = 0; j < 4; ++j)
                v[j] = *(const ushort4*)(h + (size_t)r[j].x * F + lane * 4);
            #pragma unroll
            for (int j = 0; j < 4; ++j) {
                const float wj = __int_as_float(r[j].y);
                acc[0] += b2f(v[j].x) * wj; acc[1] += b2f(v[j].y) * wj;
                acc[2] += b2f(v[j].z) * wj; acc[3] += b2f(v[j].w) * wj;
            }
        } else {
            ushort2 v[4];
            #pragma unroll
            for (int j = 0; j < 4; ++j)
                v[j] = *(const ushort2*)(h + (size_t)r[j].x * F + lane * 2);
            #pragma unroll
            for (int j = 0; j < 4; ++j) {
                const float wj = __int_as_float(r[j].y);
                acc[0] += b2f(v[j].x) * wj; acc[1] += b2f(v[j].y) * wj;
            }
        }
    }
    for (; e < e1; ++e) {
        int2 r = erec[e];
        const float wgt = __int_as_float(r.y);
        const u16* sp = h + (size_t)r.x * F + lane * VEC;
        if constexpr (VEC == 4) {
            ushort4 v = *(const ushort4*)sp;
            acc[0] += b2f(v.x) * wgt; acc[1] += b2f(v.y) * wgt;
            acc[2] += b2f(v.z) * wgt; acc[3] += b2f(v.w) * wgt;
        } else {
            ushort2 v = *(const ushort2*)sp;
            acc[0] += b2f(v.x) * wgt; acc[1] += b2f(v.y) * wgt;
        }
    }
    u16* op = out + (size_t)node * F + lane * VEC;
    if constexpr (VEC == 4) {
        ushort4 r;
        r.x = f2b(RELU ? fmaxf(acc[0], 0.f) : acc[0]);
        r.y = f2b(RELU ? fmaxf(acc[1], 0.f) : acc[1]);
        r.z = f2b(RELU ? fmaxf(acc[2], 0.f) : acc[2]);
        r.w = f2b(RELU ? fmaxf(acc[3], 0.f) : acc[3]);
        *(ushort4*)op = r;
    } else {
        ushort2 r;
        r.x = f2b(RELU ? fmaxf(acc[0], 0.f) : acc[0]);
        r.y = f2b(RELU ? fmaxf(acc[1], 0.f) : acc[1]);
        *(ushort2*)op = r;
    }
}

// final layer: h is [MP][128] bf16, logical F=64; fused log_softmax, fp32 out
__global__ __launch_bounds__(256) void agg_lsm_kernel(const u16* __restrict__ h,
        const int* __restrict__ rowptr, const int2* __restrict__ erec,
        const float* __restrict__ dinv, const float* __restrict__ bias,
        float* __restrict__ out, int N) {
    const int node = blockIdx.x * 4 + (threadIdx.x >> 6);
    if (node >= N) return;
    const int lane = threadIdx.x & 63;
    const float di = dinv[node];
    float acc = b2f(h[(size_t)node * 128 + lane]) * di * di + bias[lane];
    const int e0 = rowptr[node], e1 = rowptr[node + 1];
    int e = e0;
    for (; e + 8 <= e1; e += 8) {
        int2 r[8];
        #pragma unroll
        for (int j = 0; j < 8; ++j) r[j] = erec[e + j];
        float v[8];
        #pragma unroll
        for (int j = 0; j < 8; ++j) v[j] = b2f(h[(size_t)r[j].x * 128 + lane]);
        #pragma unroll
        for (int j = 0; j < 8; ++j) acc += v[j] * __int_as_float(r[j].y);
    }
    for (; e + 4 <= e1; e += 4) {
        int2 r[4];
        #pragma unroll
        for (int j = 0; j < 4; ++j) r[j] = erec[e + j];
        float v[4];
        #pragma unroll
        for (int j = 0; j < 4; ++j) v[j] = b2f(h[(size_t)r[j].x * 128 + lane]);
        #pragma unroll
        for (int j = 0; j < 4; ++j) acc += v[j] * __int_as_float(r[j].y);
    }
    for (; e < e1; ++e) {
        int2 r = erec[e];
        acc += b2f(h[(size_t)r.x * 128 + lane]) * __int_as_float(r.y);
    }
    float m = acc;
    #pragma unroll
    for (int o = 32; o; o >>= 1) m = fmaxf(m, __shfl_xor(m, o, 64));
    float ex = __expf(acc - m);
    float s = ex;
    #pragma unroll
    for (int o = 32; o; o >>= 1) s += __shfl_xor(s, o, 64);
    out[(size_t)node * 64 + lane] = acc - m - __logf(s);
}

// ---------------- launch ----------------

extern "C" void kernel_launch(void* const* d_in, const int* in_sizes, int n_in,
                              void* d_out, int out_size, void* d_ws, size_t ws_size,
                              hipStream_t stream) {
    const float* x  = (const float*)d_in[0];
    const int*   ei = (const int*)d_in[1];
    const float* W1 = (const float*)d_in[2];
    const float* b1 = (const float*)d_in[3];
    const float* W2 = (const float*)d_in[4];
    const float* b2 = (const float*)d_in[5];
    const float* W3 = (const float*)d_in[6];
    const float* b3 = (const float*)d_in[7];
    const int E = in_sizes[1] / 2;
    const int* src = ei;
    const int* dst = ei + E;
    const int N = NN;
    const int N4 = N / 4;                  // 25000 (N % 4 == 0)
    const int NB = (N4 + 255) / 256;       // 98 scan blocks

    char* ws = (char*)d_ws;
    int*   deg      = (int*)ws;    ws += align_up((size_t)N * 4, 256);
    int*   cursor   = (int*)ws;    ws += align_up((size_t)N * 4, 256);
    float* dinv     = (float*)ws;  ws += align_up((size_t)N * 4, 256);
    int*   rowptr   = (int*)ws;    ws += align_up((size_t)(N + 1) * 4, 256);
    int*   partials = (int*)ws;    ws += align_up((size_t)128 * 4, 256);
    int2*  erec     = (int2*)ws;   ws += align_up((size_t)E * 8, 256);
    u16*   wt1      = (u16*)ws;    ws += align_up((size_t)256 * 512 * 2, 256);
    u16*   wt2      = (u16*)ws;    ws += align_up((size_t)128 * 256 * 2, 256);
    u16*   wt3      = (u16*)ws;    ws += align_up((size_t)128 * 128 * 2, 256);
    u16*   bufH     = (u16*)ws;    ws += (size_t)MP * 256 * 2;  // h1b; later h3b
    u16*   bufAct   = (u16*)ws;    ws += (size_t)MP * 256 * 2;  // act1b / act2b
    u16*   h2b      = (u16*)ws;    ws += (size_t)MP * 128 * 2;  // h2 [MP][128]
    u16*   h3b  = bufH;
    float* out  = (float*)d_out;

    // deg and cursor are contiguous (each align_up(N*4,256)): one memset
    hipMemsetAsync(deg, 0, 2 * align_up((size_t)N * 4, 256), stream);

    deg_count_kernel<<<(E + 255) / 256, 256, 0, stream>>>(dst, deg, E);
    dinv_kernel<<<(N + 255) / 256, 256, 0, stream>>>(deg, dinv, N);
    scan_phase1<<<NB, 256, 0, stream>>>(deg, partials, N4);
    scan_phase2<<<1, 128, 0, stream>>>(partials, rowptr, NB, N);
    scan_phase3<<<NB, 256, 0, stream>>>(deg, partials, rowptr, N4);
    reorder_kernel<<<(E + 255) / 256, 256, 0, stream>>>(src, dst, rowptr, cursor, dinv, erec, E);

    transpose_kernel<<<(512 * 256 + 255) / 256, 256, 0, stream>>>(W1, wt1, 512, 256);
    transpose_kernel<<<(256 * 128 + 255) / 256, 256, 0, stream>>>(W2, wt2, 256, 128);
    transpose_kernel<<<(128 * 64 + 255) / 256, 256, 0, stream>>>(W3, wt3, 128, 64);

    const int GB = MP / 128;
    const int AB = (N + 3) / 4;

    // ---- layer 1: 512 -> 256 (fused fp32->bf16 A-convert) ----
    gemm_mfma_f32a<<<dim3(GB, 2), 256, 0, stream>>>(x, wt1, bufH, 512, 256);
    agg_kernel<4, true><<<AB, 256, 0, stream>>>(bufH, rowptr, erec, dinv, b1, bufAct, N);

    // ---- layer 2: 256 -> 128 ----
    gemm_mfma<<<dim3(GB, 1), 256, 0, stream>>>(bufAct, wt2, h2b, 256, 128);
    agg_kernel<2, true><<<AB, 256, 0, stream>>>(h2b, rowptr, erec, dinv, b2, bufAct, N);

    // ---- layer 3: 128 -> 64 (padded to 128 cols) ----
    gemm_mfma<<<dim3(GB, 1), 256, 0, stream>>>(bufAct, wt3, h3b, 128, 128);
    agg_lsm_kernel<<<AB, 256, 0, stream>>>(h3b, rowptr, erec, dinv, b3, out, N);
}